// Round 2
// baseline (5024.963 us; speedup 1.0000x reference)
//
#include <hip/hip_runtime.h>
#include <hip/hip_bf16.h>
#include <stdint.h>

#define TOK 16384   // B*S
#define DD  1024    // D = F = 1024
#define NE  32      // experts

typedef unsigned short u16;
typedef __attribute__((ext_vector_type(8))) short short8;
typedef __attribute__((ext_vector_type(4))) float f32x4;

__device__ __forceinline__ u16 f2bf(float f) {
  unsigned int u = __float_as_uint(f);
  u += 0x7fffu + ((u >> 16) & 1u);
  return (u16)(u >> 16);
}
__device__ __forceinline__ float bf2f(u16 h) {
  return __uint_as_float(((unsigned int)h) << 16);
}
__device__ __forceinline__ void gload16(const void* g, void* l) {
  __builtin_amdgcn_global_load_lds((const __attribute__((address_space(1))) void*)g,
                                   (__attribute__((address_space(3))) void*)l, 16, 0, 0);
}

// ---------------- transpose + convert: src[z][R][C] f32 -> dst[z][C][R] (bf16 or f32)
template <typename OT>
__global__ __launch_bounds__(256) void k_transpose(const float* __restrict__ src,
                                                   OT* __restrict__ dst, int R, int C) {
  __shared__ float tile[32][33];
  size_t mb = (size_t)blockIdx.z * R * C;
  int c0 = blockIdx.x * 32, r0 = blockIdx.y * 32;
  int tx = threadIdx.x, ty = threadIdx.y;
#pragma unroll
  for (int i = 0; i < 4; i++)
    tile[ty + i * 8][tx] = src[mb + (size_t)(r0 + ty + i * 8) * C + c0 + tx];
  __syncthreads();
#pragma unroll
  for (int i = 0; i < 4; i++) {
    float v = tile[tx][ty + i * 8];
    if constexpr (sizeof(OT) == 2)
      dst[mb + (size_t)(c0 + ty + i * 8) * R + r0 + tx] = f2bf(v);
    else
      dst[mb + (size_t)(c0 + ty + i * 8) * R + r0 + tx] = v;
  }
}

// ---------------- transpose + split into bf16 hi/lo pair: dst[C][R]
__global__ __launch_bounds__(256) void k_transpose_split(const float* __restrict__ src,
                                                         u16* __restrict__ hi,
                                                         u16* __restrict__ lo, int R, int C) {
  __shared__ float tile[32][33];
  int c0 = blockIdx.x * 32, r0 = blockIdx.y * 32;
  int tx = threadIdx.x, ty = threadIdx.y;
#pragma unroll
  for (int i = 0; i < 4; i++)
    tile[ty + i * 8][tx] = src[(size_t)(r0 + ty + i * 8) * C + c0 + tx];
  __syncthreads();
#pragma unroll
  for (int i = 0; i < 4; i++) {
    float v = tile[tx][ty + i * 8];
    u16 h = f2bf(v);
    u16 l = f2bf(v - bf2f(h));
    size_t idx = (size_t)(c0 + ty + i * 8) * R + r0 + tx;
    hi[idx] = h;
    lo[idx] = l;
  }
}

// ---------------- LN1: x = LN(hidden) -> bf16 hi/lo pair
__global__ __launch_bounds__(256) void k_ln1(const float* __restrict__ x,
                                             const float* __restrict__ sc,
                                             const float* __restrict__ bi,
                                             u16* __restrict__ ohi, u16* __restrict__ olo) {
  __shared__ float red[10];
  int t = blockIdx.x, tid = threadIdx.x;
  size_t base = (size_t)t * DD + tid * 4;
  float4 v = *(const float4*)(x + base);
  float s1 = v.x + v.y + v.z + v.w;
  float s2 = v.x * v.x + v.y * v.y + v.z * v.z + v.w * v.w;
  for (int o = 1; o < 64; o <<= 1) { s1 += __shfl_xor(s1, o, 64); s2 += __shfl_xor(s2, o, 64); }
  int wid = tid >> 6;
  if ((tid & 63) == 0) { red[wid * 2] = s1; red[wid * 2 + 1] = s2; }
  __syncthreads();
  if (tid == 0) {
    float a = 0, b = 0;
    for (int i = 0; i < 4; i++) { a += red[i * 2]; b += red[i * 2 + 1]; }
    float mean = a * (1.f / DD);
    float var = b * (1.f / DD) - mean * mean;
    red[8] = mean; red[9] = rsqrtf(var + 1e-5f);
  }
  __syncthreads();
  float mean = red[8], rs = red[9];
  int e0 = tid * 4;
  float xv[4] = {v.x, v.y, v.z, v.w};
  ushort4 oh, ol;
  u16* ph = (u16*)&oh; u16* pl = (u16*)&ol;
#pragma unroll
  for (int i = 0; i < 4; i++) {
    float f = (xv[i] - mean) * rs * sc[e0 + i] + bi[e0 + i];
    u16 h = f2bf(f);
    ph[i] = h;
    pl[i] = f2bf(f - bf2f(h));
  }
  *(ushort4*)(ohi + base) = oh;
  *(ushort4*)(olo + base) = ol;
}

// ---------------- fused: per-token head attention + residual + LN2 + router + top-8 gates
__global__ __launch_bounds__(256) void k_attn(
    const float* __restrict__ hidden, const float* __restrict__ qb,
    const float* __restrict__ kb, const float* __restrict__ vb,
    const float* __restrict__ ln2s, const float* __restrict__ ln2b,
    const float* __restrict__ rwT, const float* __restrict__ rb,
    float* __restrict__ out, u16* __restrict__ x2b, float* __restrict__ gates) {
  __shared__ float qs[16][68], ks[16][68], vs[16][68];
  __shared__ float probs[16][17];
  __shared__ float x2s[1024];
  __shared__ float red[12];
  __shared__ float logits[32];
  int t = blockIdx.x, tid = threadIdx.x;
  size_t base = (size_t)t * DD + tid * 4;
  int hh = tid >> 4, dd = (tid & 15) * 4;
  {
    float4 q4 = *(const float4*)(qb + base);
    float4 k4 = *(const float4*)(kb + base);
    float4 v4 = *(const float4*)(vb + base);
    qs[hh][dd + 0] = q4.x; qs[hh][dd + 1] = q4.y; qs[hh][dd + 2] = q4.z; qs[hh][dd + 3] = q4.w;
    ks[hh][dd + 0] = k4.x; ks[hh][dd + 1] = k4.y; ks[hh][dd + 2] = k4.z; ks[hh][dd + 3] = k4.w;
    vs[hh][dd + 0] = v4.x; vs[hh][dd + 1] = v4.y; vs[hh][dd + 2] = v4.z; vs[hh][dd + 3] = v4.w;
  }
  __syncthreads();
  {
    int g = tid & 15;
    float s = 0.f;
#pragma unroll
    for (int d = 0; d < 64; d++) s += qs[hh][d] * ks[g][d];
    s *= 0.125f;
    float mx = s;
    for (int o = 1; o < 16; o <<= 1) mx = fmaxf(mx, __shfl_xor(mx, o, 16));
    float p = __expf(s - mx);
    float sm = p;
    for (int o = 1; o < 16; o <<= 1) sm += __shfl_xor(sm, o, 16);
    probs[hh][g] = p / sm;
  }
  __syncthreads();
  float c0 = 0, c1 = 0, c2 = 0, c3 = 0;
#pragma unroll
  for (int g = 0; g < 16; g++) {
    float pw = probs[hh][g];
    c0 += pw * vs[g][dd + 0]; c1 += pw * vs[g][dd + 1];
    c2 += pw * vs[g][dd + 2]; c3 += pw * vs[g][dd + 3];
  }
  float4 hv = *(const float4*)(hidden + base);
  float h0 = hv.x + c0, h1 = hv.y + c1, h2 = hv.z + c2, h3 = hv.w + c3;
  { float4 o4; o4.x = h0; o4.y = h1; o4.z = h2; o4.w = h3; *(float4*)(out + base) = o4; }
  float s1 = h0 + h1 + h2 + h3;
  float s2 = h0 * h0 + h1 * h1 + h2 * h2 + h3 * h3;
  for (int o = 1; o < 64; o <<= 1) { s1 += __shfl_xor(s1, o, 64); s2 += __shfl_xor(s2, o, 64); }
  int wid = tid >> 6;
  if ((tid & 63) == 0) { red[wid * 2] = s1; red[wid * 2 + 1] = s2; }
  __syncthreads();
  if (tid == 0) {
    float a = 0, b = 0;
    for (int i = 0; i < 4; i++) { a += red[i * 2]; b += red[i * 2 + 1]; }
    float mean = a * (1.f / DD);
    float var = b * (1.f / DD) - mean * mean;
    red[8] = mean; red[9] = rsqrtf(var + 1e-5f);
  }
  __syncthreads();
  float mean = red[8], rs = red[9];
  int e0 = tid * 4;
  float x0 = (h0 - mean) * rs * ln2s[e0 + 0] + ln2b[e0 + 0];
  float x1 = (h1 - mean) * rs * ln2s[e0 + 1] + ln2b[e0 + 1];
  float x2 = (h2 - mean) * rs * ln2s[e0 + 2] + ln2b[e0 + 2];
  float x3 = (h3 - mean) * rs * ln2s[e0 + 3] + ln2b[e0 + 3];
  ushort4 xo; xo.x = f2bf(x0); xo.y = f2bf(x1); xo.z = f2bf(x2); xo.w = f2bf(x3);
  *(ushort4*)(x2b + base) = xo;
  x2s[e0 + 0] = x0; x2s[e0 + 1] = x1; x2s[e0 + 2] = x2; x2s[e0 + 3] = x3;
  __syncthreads();
  {
    int e = tid >> 3, j = tid & 7;
    const float* wr_ = rwT + (size_t)e * DD + j * 128;
    float acc = 0.f;
#pragma unroll 4
    for (int i = 0; i < 128; i += 4) {
      float4 w4 = *(const float4*)(wr_ + i);
      float4 xv = *(const float4*)(&x2s[j * 128 + i]);
      acc += w4.x * xv.x + w4.y * xv.y + w4.z * xv.z + w4.w * xv.w;
    }
    for (int o = 1; o < 8; o <<= 1) acc += __shfl_xor(acc, o, 8);
    if (j == 0) logits[e] = acc + rb[e];
  }
  __syncthreads();
  if (tid < 32) {
    float l = logits[tid];
    float mx = l;
    for (int o = 1; o < 32; o <<= 1) mx = fmaxf(mx, __shfl_xor(mx, o, 32));
    float p = __expf(l - mx);
    float sm = p;
    for (int o = 1; o < 32; o <<= 1) sm += __shfl_xor(sm, o, 32);
    p /= sm;
    bool sel = false;
#pragma unroll
    for (int rsel = 0; rsel < 8; rsel++) {
      float bv = sel ? -1.f : p;
      int bi_ = tid;
      for (int o = 1; o < 32; o <<= 1) {
        float ov = __shfl_xor(bv, o, 32);
        int oi = __shfl_xor(bi_, o, 32);
        if (ov > bv || (ov == bv && oi < bi_)) { bv = ov; bi_ = oi; }
      }
      if (tid == bi_) sel = true;
    }
    float wsel = sel ? p : 0.f;
    float ts = wsel;
    for (int o = 1; o < 32; o <<= 1) ts += __shfl_xor(ts, o, 32);
    gates[(size_t)t * 32 + tid] = sel ? (p / ts) : 0.f;
  }
}

__global__ void k_zero32(int* p) { int i = threadIdx.x; if (i < 32) p[i] = 0; }

__global__ void k_listbuild(const float* __restrict__ gates, int* __restrict__ counts,
                            int* __restrict__ lists) {
  int t = blockIdx.x * 256 + threadIdx.x;
  for (int e = 0; e < NE; e++) {
    if (gates[(size_t)t * 32 + e] > 0.f) {
      int pos = atomicAdd(&counts[e], 1);
      lists[(size_t)e * TOK + pos] = t;
    }
  }
}

__global__ void k_scan(const int* __restrict__ counts, int* __restrict__ segoff) {
  if (threadIdx.x == 0) { int s = 0; for (int e = 0; e < NE; e++) { segoff[e] = s; s += counts[e]; } }
}

// ---------------- precise GEMM (split bf16): C = (Ahi+Alo)@(Bhi+Blo)^T + bias -> fp32
// computes hi*hi + hi*lo + lo*hi (drops lo*lo, rel err ~2^-16)
__global__ __launch_bounds__(256) void k_gemm_p(
    const u16* __restrict__ Ahi, const u16* __restrict__ Alo,
    const u16* __restrict__ Bhi, const u16* __restrict__ Blo,
    const float* __restrict__ bias, float* __restrict__ C) {
  constexpr int KD = 1024;
  __shared__ alignas(16) u16 As[2][2][128 * 32];  // [buf][hi/lo]
  __shared__ alignas(16) u16 Bs[2][2][128 * 32];
  const int tid = threadIdx.x;
  const int w = tid >> 6, lane = tid & 63;
  const int bm = blockIdx.x, bn = blockIdx.y;

  int rowA[2], qA[2], rowB[2];
#pragma unroll
  for (int i = 0; i < 2; i++) {
    int c = (w * 2 + i) * 64 + lane;
    int r = c >> 2;
    qA[i] = c & 3;
    rowB[i] = bn * 128 + r;
    rowA[i] = bm * 128 + r;
  }

  auto stage = [&](int buf, int k0) {
#pragma unroll
    for (int i = 0; i < 2; i++) {
      size_t ga = (size_t)rowA[i] * KD + k0 + qA[i] * 8;
      size_t gb = (size_t)rowB[i] * KD + k0 + qA[i] * 8;
      int lo_off = (w * 2 + i) * 1024;
      gload16(Ahi + ga, (char*)&As[buf][0][0] + lo_off);
      gload16(Alo + ga, (char*)&As[buf][1][0] + lo_off);
      gload16(Bhi + gb, (char*)&Bs[buf][0][0] + lo_off);
      gload16(Blo + gb, (char*)&Bs[buf][1][0] + lo_off);
    }
  };

  f32x4 acc[4][4];
#pragma unroll
  for (int m = 0; m < 4; m++)
#pragma unroll
    for (int n = 0; n < 4; n++) acc[m][n] = (f32x4)0.f;

  const int wr = (w >> 1) * 64, wc = (w & 1) * 64;
  const int la = lane & 15, lk = (lane >> 4) * 8;

  stage(0, 0);
  __syncthreads();
  for (int kt = 0; kt < 32; kt++) {
    const int cur = kt & 1;
    if (kt + 1 < 32) stage(cur ^ 1, (kt + 1) * 32);
    short8 ah[4], al[4], bh[4], bl[4];
#pragma unroll
    for (int m = 0; m < 4; m++) {
      ah[m] = *(const short8*)&As[cur][0][(wr + m * 16 + la) * 32 + lk];
      al[m] = *(const short8*)&As[cur][1][(wr + m * 16 + la) * 32 + lk];
    }
#pragma unroll
    for (int n = 0; n < 4; n++) {
      bh[n] = *(const short8*)&Bs[cur][0][(wc + n * 16 + la) * 32 + lk];
      bl[n] = *(const short8*)&Bs[cur][1][(wc + n * 16 + la) * 32 + lk];
    }
#pragma unroll
    for (int m = 0; m < 4; m++)
#pragma unroll
      for (int n = 0; n < 4; n++) {
        acc[m][n] = __builtin_amdgcn_mfma_f32_16x16x32_bf16(ah[m], bh[n], acc[m][n], 0, 0, 0);
        acc[m][n] = __builtin_amdgcn_mfma_f32_16x16x32_bf16(ah[m], bl[n], acc[m][n], 0, 0, 0);
        acc[m][n] = __builtin_amdgcn_mfma_f32_16x16x32_bf16(al[m], bh[n], acc[m][n], 0, 0, 0);
      }
    __syncthreads();
  }

  const int rl4 = (lane >> 4) * 4;
#pragma unroll
  for (int m = 0; m < 4; m++) {
#pragma unroll
    for (int n = 0; n < 4; n++) {
      const int col = bn * 128 + wc + n * 16 + la;
      const float bvv = bias[col];
      f32x4 a4 = acc[m][n];
#pragma unroll
      for (int r = 0; r < 4; r++) {
        const int grow = bm * 128 + wr + m * 16 + rl4 + r;
        C[(size_t)grow * KD + col] = a4[r] + bvv;
      }
    }
  }
}

// ---------------- MFMA GEMM, 128x128 tile, BK=32, double-buffered global_load_lds.
// MODE 1: gathered rows (expert token list), gelu(.+b1) -> h_buf rows segoff+pos
// MODE 2: A = h_buf rows, (.+b2)*gate -> atomicAdd scatter into out
template <int MODE>
__global__ __launch_bounds__(256) void k_gemm(
    const u16* __restrict__ A, const u16* __restrict__ BT, const float* __restrict__ bias,
    u16* __restrict__ Cb, float* __restrict__ Cf,
    const int* __restrict__ lists, const int* __restrict__ counts,
    const float* __restrict__ gatesp, const int* __restrict__ segoff, int ebase) {
  constexpr int KD = 1024;
  __shared__ alignas(16) u16 As[2][128 * 32];
  __shared__ alignas(16) u16 Bs[2][128 * 32];

  int e = ebase + (int)blockIdx.z;
  int count = counts[e];
  if ((int)blockIdx.x * 128 >= count) return;
  const int* list = lists + (size_t)e * TOK;
  int so = (segoff != nullptr) ? segoff[e] : 0;
  const u16* Bp = BT + (size_t)e * (KD * KD);
  const float* bp = bias + (size_t)e * KD;

  const int tid = threadIdx.x;
  const int w = tid >> 6, lane = tid & 63;
  const int bm = blockIdx.x, bn = blockIdx.y;

  int rowA[2], qA[2], rowB[2];
#pragma unroll
  for (int i = 0; i < 2; i++) {
    int c = (w * 2 + i) * 64 + lane;
    int r = c >> 2;
    qA[i] = c & 3;
    rowB[i] = bn * 128 + r;
    int rr = bm * 128 + r;
    if constexpr (MODE == 1) rowA[i] = (rr < count) ? list[rr] : 0;
    else                     rowA[i] = so + ((rr < count) ? rr : 0);
  }

  auto stage = [&](int buf, int k0) {
#pragma unroll
    for (int i = 0; i < 2; i++) {
      gload16(A + (size_t)rowA[i] * KD + k0 + qA[i] * 8,
              (char*)&As[buf][0] + (w * 2 + i) * 1024);
      gload16(Bp + (size_t)rowB[i] * KD + k0 + qA[i] * 8,
              (char*)&Bs[buf][0] + (w * 2 + i) * 1024);
    }
  };

  f32x4 acc[4][4];
#pragma unroll
  for (int m = 0; m < 4; m++)
#pragma unroll
    for (int n = 0; n < 4; n++) acc[m][n] = (f32x4)0.f;

  const int wr = (w >> 1) * 64, wc = (w & 1) * 64;
  const int la = lane & 15, lk = (lane >> 4) * 8;

  stage(0, 0);
  __syncthreads();
#pragma unroll 2
  for (int kt = 0; kt < 32; kt++) {
    const int cur = kt & 1;
    if (kt + 1 < 32) stage(cur ^ 1, (kt + 1) * 32);
    short8 af[4], bf8[4];
#pragma unroll
    for (int m = 0; m < 4; m++)
      af[m] = *(const short8*)&As[cur][(wr + m * 16 + la) * 32 + lk];
#pragma unroll
    for (int n = 0; n < 4; n++)
      bf8[n] = *(const short8*)&Bs[cur][(wc + n * 16 + la) * 32 + lk];
#pragma unroll
    for (int m = 0; m < 4; m++)
#pragma unroll
      for (int n = 0; n < 4; n++)
        acc[m][n] = __builtin_amdgcn_mfma_f32_16x16x32_bf16(af[m], bf8[n], acc[m][n], 0, 0, 0);
    __syncthreads();
  }

  const int rl4 = (lane >> 4) * 4;
#pragma unroll
  for (int m = 0; m < 4; m++) {
#pragma unroll
    for (int n = 0; n < 4; n++) {
      const int col = bn * 128 + wc + n * 16 + la;
      const float bvv = bp[col];
      f32x4 a4 = acc[m][n];
#pragma unroll
      for (int r = 0; r < 4; r++) {
        const int grow = bm * 128 + wr + m * 16 + rl4 + r;
        float v = a4[r] + bvv;
        if constexpr (MODE == 1) {
          if (grow < count) {
            float gx = 0.5f * v * (1.0f + erff(v * 0.70710678f));
            Cb[(size_t)(so + grow) * KD + col] = f2bf(gx);
          }
        } else {
          if (grow < count) {
            const int tok = list[grow];
            const float gw = gatesp[(size_t)tok * 32 + e];
            atomicAdd(Cf + (size_t)tok * KD + col, v * gw);
          }
        }
      }
    }
  }
}

extern "C" void kernel_launch(void* const* d_in, const int* in_sizes, int n_in,
                              void* d_out, int out_size, void* d_ws, size_t ws_size,
                              hipStream_t stream) {
  (void)in_sizes; (void)n_in; (void)out_size;
  const float* hidden = (const float*)d_in[0];
  const float* ln1s = (const float*)d_in[1];
  const float* ln1b = (const float*)d_in[2];
  const float* wq = (const float*)d_in[3];
  const float* bq = (const float*)d_in[4];
  const float* wk = (const float*)d_in[5];
  const float* bk = (const float*)d_in[6];
  const float* wv = (const float*)d_in[7];
  const float* bv = (const float*)d_in[8];
  const float* ln2s = (const float*)d_in[9];
  const float* ln2b = (const float*)d_in[10];
  const float* rw = (const float*)d_in[11];
  const float* rb = (const float*)d_in[12];
  const float* w1 = (const float*)d_in[13];
  const float* b1 = (const float*)d_in[14];
  const float* w2 = (const float*)d_in[15];
  const float* b2 = (const float*)d_in[16];
  float* out = (float*)d_out;

  char* wsp = (char*)d_ws;
  size_t off = 0;
  auto alloc = [&](size_t b) -> void* {
    void* p = wsp + off;
    off += (b + 255) & ~(size_t)255;
    return p;
  };
  u16* wqTh = (u16*)alloc((size_t)DD * DD * 2);
  u16* wqTl = (u16*)alloc((size_t)DD * DD * 2);
  u16* wkTh = (u16*)alloc((size_t)DD * DD * 2);
  u16* wkTl = (u16*)alloc((size_t)DD * DD * 2);
  u16* wvTh = (u16*)alloc((size_t)DD * DD * 2);
  u16* wvTl = (u16*)alloc((size_t)DD * DD * 2);
  u16* w1T = (u16*)alloc((size_t)NE * DD * DD * 2);
  u16* w2T = (u16*)alloc((size_t)NE * DD * DD * 2);
  float* rwT = (float*)alloc((size_t)NE * DD * 4);
  u16* x_hi = (u16*)alloc((size_t)TOK * DD * 2);   // ln1 out hi; reused as x2 bf16
  u16* x_lo = (u16*)alloc((size_t)TOK * DD * 2);
  float* gates = (float*)alloc((size_t)TOK * NE * 4);
  int* counts = (int*)alloc(NE * 4);
  int* segoff = (int*)alloc((NE + 1) * 4);
  int* lists = (int*)alloc((size_t)NE * TOK * 4);
  float* qbuf = (float*)alloc((size_t)TOK * DD * 4);
  float* kbuf = (float*)alloc((size_t)TOK * DD * 4);
  float* vbuf = (float*)alloc((size_t)TOK * DD * 4);

  size_t hbuf_bytes = (size_t)TOK * 8 * DD * 2;  // 131072 rows x 1024 bf16 = 256 MiB
  bool big = (off + hbuf_bytes + 256) <= ws_size;
  u16* h_buf = big ? (u16*)alloc(hbuf_bytes) : (u16*)kbuf;  // seq path reuses dead kbuf

  dim3 tb32(32, 8, 1);
  k_zero32<<<1, 64, 0, stream>>>(counts);
  k_transpose_split<<<dim3(32, 32, 1), tb32, 0, stream>>>(wq, wqTh, wqTl, DD, DD);
  k_transpose_split<<<dim3(32, 32, 1), tb32, 0, stream>>>(wk, wkTh, wkTl, DD, DD);
  k_transpose_split<<<dim3(32, 32, 1), tb32, 0, stream>>>(wv, wvTh, wvTl, DD, DD);
  k_transpose<u16><<<dim3(32, 32, NE), tb32, 0, stream>>>(w1, w1T, DD, DD);
  k_transpose<u16><<<dim3(32, 32, NE), tb32, 0, stream>>>(w2, w2T, DD, DD);
  k_transpose<float><<<dim3(1, 32, 1), tb32, 0, stream>>>(rw, rwT, DD, NE);
  k_ln1<<<TOK, 256, 0, stream>>>(hidden, ln1s, ln1b, x_hi, x_lo);
  k_gemm_p<<<dim3(128, 8, 1), 256, 0, stream>>>(x_hi, x_lo, wqTh, wqTl, bq, qbuf);
  k_gemm_p<<<dim3(128, 8, 1), 256, 0, stream>>>(x_hi, x_lo, wkTh, wkTl, bk, kbuf);
  k_gemm_p<<<dim3(128, 8, 1), 256, 0, stream>>>(x_hi, x_lo, wvTh, wvTl, bv, vbuf);
  k_attn<<<TOK, 256, 0, stream>>>(hidden, qbuf, kbuf, vbuf, ln2s, ln2b, rwT, rb, out, x_hi, gates);
  k_listbuild<<<TOK / 256, 256, 0, stream>>>(gates, counts, lists);
  if (big) {
    k_scan<<<1, 32, 0, stream>>>(counts, segoff);
    k_gemm<1><<<dim3(128, 8, NE), 256, 0, stream>>>(x_hi, w1T, b1, h_buf, nullptr, lists, counts, nullptr, segoff, 0);
    k_gemm<2><<<dim3(128, 8, NE), 256, 0, stream>>>(h_buf, w2T, b2, nullptr, out, lists, counts, gates, segoff, 0);
  } else {
    for (int e = 0; e < NE; e++) {
      k_gemm<1><<<dim3(128, 8, 1), 256, 0, stream>>>(x_hi, w1T, b1, h_buf, nullptr, lists, counts, nullptr, nullptr, e);
      k_gemm<2><<<dim3(128, 8, 1), 256, 0, stream>>>(h_buf, w2T, b2, nullptr, out, lists, counts, gates, nullptr, e);
    }
  }
}

// Round 3
// 2531.542 us; speedup vs baseline: 1.9849x; 1.9849x over previous
//
#include <hip/hip_runtime.h>
#include <hip/hip_bf16.h>
#include <stdint.h>

#define TOK 16384   // B*S
#define DD  1024    // D = F = 1024
#define NE  32      // experts

typedef unsigned short u16;
typedef __attribute__((ext_vector_type(8))) short short8;
typedef __attribute__((ext_vector_type(4))) float f32x4;

__device__ __forceinline__ u16 f2bf(float f) {
  unsigned int u = __float_as_uint(f);
  u += 0x7fffu + ((u >> 16) & 1u);
  return (u16)(u >> 16);
}
__device__ __forceinline__ float bf2f(u16 h) {
  return __uint_as_float(((unsigned int)h) << 16);
}
__device__ __forceinline__ void gload16(const void* g, void* l) {
  __builtin_amdgcn_global_load_lds((const __attribute__((address_space(1))) void*)g,
                                   (__attribute__((address_space(3))) void*)l, 16, 0, 0);
}

// ---------------- transpose + convert: src[z][R][C] f32 -> dst[z][C][R] bf16
__global__ __launch_bounds__(256) void k_transpose(const float* __restrict__ src,
                                                   u16* __restrict__ dst, int R, int C) {
  __shared__ float tile[32][33];
  size_t mb = (size_t)blockIdx.z * R * C;
  int c0 = blockIdx.x * 32, r0 = blockIdx.y * 32;
  int tx = threadIdx.x, ty = threadIdx.y;
#pragma unroll
  for (int i = 0; i < 4; i++)
    tile[ty + i * 8][tx] = src[mb + (size_t)(r0 + ty + i * 8) * C + c0 + tx];
  __syncthreads();
#pragma unroll
  for (int i = 0; i < 4; i++) {
    float v = tile[tx][ty + i * 8];
    dst[mb + (size_t)(c0 + ty + i * 8) * R + r0 + tx] = f2bf(v);
  }
}

// ---------------- transpose + split into bf16 hi/lo pair: dst[C][R]
__global__ __launch_bounds__(256) void k_transpose_split(const float* __restrict__ src,
                                                         u16* __restrict__ hi,
                                                         u16* __restrict__ lo, int R, int C) {
  __shared__ float tile[32][33];
  int c0 = blockIdx.x * 32, r0 = blockIdx.y * 32;
  int tx = threadIdx.x, ty = threadIdx.y;
#pragma unroll
  for (int i = 0; i < 4; i++)
    tile[ty + i * 8][tx] = src[(size_t)(r0 + ty + i * 8) * C + c0 + tx];
  __syncthreads();
#pragma unroll
  for (int i = 0; i < 4; i++) {
    float v = tile[tx][ty + i * 8];
    u16 h = f2bf(v);
    u16 l = f2bf(v - bf2f(h));
    size_t idx = (size_t)(c0 + ty + i * 8) * R + r0 + tx;
    hi[idx] = h;
    lo[idx] = l;
  }
}

// ---------------- LN1: x = LN(hidden) -> bf16 hi/lo pair
__global__ __launch_bounds__(256) void k_ln1(const float* __restrict__ x,
                                             const float* __restrict__ sc,
                                             const float* __restrict__ bi,
                                             u16* __restrict__ ohi, u16* __restrict__ olo) {
  __shared__ float red[10];
  int t = blockIdx.x, tid = threadIdx.x;
  size_t base = (size_t)t * DD + tid * 4;
  float4 v = *(const float4*)(x + base);
  float s1 = v.x + v.y + v.z + v.w;
  float s2 = v.x * v.x + v.y * v.y + v.z * v.z + v.w * v.w;
  for (int o = 1; o < 64; o <<= 1) { s1 += __shfl_xor(s1, o, 64); s2 += __shfl_xor(s2, o, 64); }
  int wid = tid >> 6;
  if ((tid & 63) == 0) { red[wid * 2] = s1; red[wid * 2 + 1] = s2; }
  __syncthreads();
  if (tid == 0) {
    float a = 0, b = 0;
    for (int i = 0; i < 4; i++) { a += red[i * 2]; b += red[i * 2 + 1]; }
    float mean = a * (1.f / DD);
    float var = b * (1.f / DD) - mean * mean;
    red[8] = mean; red[9] = rsqrtf(var + 1e-5f);
  }
  __syncthreads();
  float mean = red[8], rs = red[9];
  int e0 = tid * 4;
  float xv[4] = {v.x, v.y, v.z, v.w};
  ushort4 oh, ol;
  u16* ph = (u16*)&oh; u16* pl = (u16*)&ol;
#pragma unroll
  for (int i = 0; i < 4; i++) {
    float f = (xv[i] - mean) * rs * sc[e0 + i] + bi[e0 + i];
    u16 h = f2bf(f);
    ph[i] = h;
    pl[i] = f2bf(f - bf2f(h));
  }
  *(ushort4*)(ohi + base) = oh;
  *(ushort4*)(olo + base) = ol;
}

// ---------------- fused: per-token head attention + residual + LN2 + router + top-8 gates
__global__ __launch_bounds__(256) void k_attn(
    const float* __restrict__ hidden, const float* __restrict__ qb,
    const float* __restrict__ kb, const float* __restrict__ vb,
    const float* __restrict__ ln2s, const float* __restrict__ ln2b,
    const float* __restrict__ rw, const float* __restrict__ rb,
    float* __restrict__ out, u16* __restrict__ x2b, float* __restrict__ gates) {
  __shared__ float qs[16][68], ks[16][68], vs[16][68];
  __shared__ float probs[16][17];
  __shared__ float x2s[1024];
  __shared__ float red[12];
  __shared__ float part[8][32];
  __shared__ float logits[32];
  int t = blockIdx.x, tid = threadIdx.x;
  size_t base = (size_t)t * DD + tid * 4;
  int hh = tid >> 4, dd = (tid & 15) * 4;
  {
    float4 q4 = *(const float4*)(qb + base);
    float4 k4 = *(const float4*)(kb + base);
    float4 v4 = *(const float4*)(vb + base);
    qs[hh][dd + 0] = q4.x; qs[hh][dd + 1] = q4.y; qs[hh][dd + 2] = q4.z; qs[hh][dd + 3] = q4.w;
    ks[hh][dd + 0] = k4.x; ks[hh][dd + 1] = k4.y; ks[hh][dd + 2] = k4.z; ks[hh][dd + 3] = k4.w;
    vs[hh][dd + 0] = v4.x; vs[hh][dd + 1] = v4.y; vs[hh][dd + 2] = v4.z; vs[hh][dd + 3] = v4.w;
  }
  __syncthreads();
  {
    int g = tid & 15;
    float s = 0.f;
#pragma unroll
    for (int d = 0; d < 64; d++) s += qs[hh][d] * ks[g][d];
    s *= 0.125f;
    float mx = s;
    for (int o = 1; o < 16; o <<= 1) mx = fmaxf(mx, __shfl_xor(mx, o, 16));
    float p = __expf(s - mx);
    float sm = p;
    for (int o = 1; o < 16; o <<= 1) sm += __shfl_xor(sm, o, 16);
    probs[hh][g] = p / sm;
  }
  __syncthreads();
  float c0 = 0, c1 = 0, c2 = 0, c3 = 0;
#pragma unroll
  for (int g = 0; g < 16; g++) {
    float pw = probs[hh][g];
    c0 += pw * vs[g][dd + 0]; c1 += pw * vs[g][dd + 1];
    c2 += pw * vs[g][dd + 2]; c3 += pw * vs[g][dd + 3];
  }
  float4 hv = *(const float4*)(hidden + base);
  float h0 = hv.x + c0, h1 = hv.y + c1, h2 = hv.z + c2, h3 = hv.w + c3;
  { float4 o4; o4.x = h0; o4.y = h1; o4.z = h2; o4.w = h3; *(float4*)(out + base) = o4; }
  float s1 = h0 + h1 + h2 + h3;
  float s2 = h0 * h0 + h1 * h1 + h2 * h2 + h3 * h3;
  for (int o = 1; o < 64; o <<= 1) { s1 += __shfl_xor(s1, o, 64); s2 += __shfl_xor(s2, o, 64); }
  int wid = tid >> 6;
  if ((tid & 63) == 0) { red[wid * 2] = s1; red[wid * 2 + 1] = s2; }
  __syncthreads();
  if (tid == 0) {
    float a = 0, b = 0;
    for (int i = 0; i < 4; i++) { a += red[i * 2]; b += red[i * 2 + 1]; }
    float mean = a * (1.f / DD);
    float var = b * (1.f / DD) - mean * mean;
    red[8] = mean; red[9] = rsqrtf(var + 1e-5f);
  }
  __syncthreads();
  float mean = red[8], rs = red[9];
  int e0 = tid * 4;
  float x0 = (h0 - mean) * rs * ln2s[e0 + 0] + ln2b[e0 + 0];
  float x1 = (h1 - mean) * rs * ln2s[e0 + 1] + ln2b[e0 + 1];
  float x2 = (h2 - mean) * rs * ln2s[e0 + 2] + ln2b[e0 + 2];
  float x3 = (h3 - mean) * rs * ln2s[e0 + 3] + ln2b[e0 + 3];
  ushort4 xo; xo.x = f2bf(x0); xo.y = f2bf(x1); xo.z = f2bf(x2); xo.w = f2bf(x3);
  *(ushort4*)(x2b + base) = xo;
  x2s[e0 + 0] = x0; x2s[e0 + 1] = x1; x2s[e0 + 2] = x2; x2s[e0 + 3] = x3;
  __syncthreads();
  {
    // router GEMV: e = tid&31 (coalesced rw), seg = tid>>5 (x2s broadcast)
    int e = tid & 31, seg = tid >> 5;
    const float* rwp = rw + (size_t)(seg * 128) * NE + e;
    float acc = 0.f;
#pragma unroll 8
    for (int i = 0; i < 128; i++) acc += x2s[seg * 128 + i] * rwp[(size_t)i * NE];
    part[seg][e] = acc;
  }
  __syncthreads();
  if (tid < 32) {
    float l = rb[tid];
#pragma unroll
    for (int s = 0; s < 8; s++) l += part[s][tid];
    logits[tid] = l;
    float mx = l;
    for (int o = 1; o < 32; o <<= 1) mx = fmaxf(mx, __shfl_xor(mx, o, 32));
    float p = __expf(l - mx);
    float sm = p;
    for (int o = 1; o < 32; o <<= 1) sm += __shfl_xor(sm, o, 32);
    p /= sm;
    bool sel = false;
#pragma unroll
    for (int rsel = 0; rsel < 8; rsel++) {
      float bv = sel ? -1.f : p;
      int bi_ = tid;
      for (int o = 1; o < 32; o <<= 1) {
        float ov = __shfl_xor(bv, o, 32);
        int oi = __shfl_xor(bi_, o, 32);
        if (ov > bv || (ov == bv && oi < bi_)) { bv = ov; bi_ = oi; }
      }
      if (tid == bi_) sel = true;
    }
    float wsel = sel ? p : 0.f;
    float ts = wsel;
    for (int o = 1; o < 32; o <<= 1) ts += __shfl_xor(ts, o, 32);
    gates[(size_t)t * 32 + tid] = sel ? (p / ts) : 0.f;
  }
}

__global__ void k_zero32(int* p) { int i = threadIdx.x; if (i < 32) p[i] = 0; }

__global__ void k_listbuild(const float* __restrict__ gates, int* __restrict__ counts,
                            int* __restrict__ lists) {
  int t = blockIdx.x * 256 + threadIdx.x;
  for (int e = 0; e < NE; e++) {
    if (gates[(size_t)t * 32 + e] > 0.f) {
      int pos = atomicAdd(&counts[e], 1);
      lists[(size_t)e * TOK + pos] = t;
    }
  }
}

__global__ void k_scan(const int* __restrict__ counts, int* __restrict__ segoff) {
  if (threadIdx.x == 0) { int s = 0; for (int e = 0; e < NE; e++) { segoff[e] = s; s += counts[e]; } }
}

// ---------------- precise GEMM (split bf16), z = matrix select (Q/K/V)
__global__ __launch_bounds__(256) void k_gemm_p(
    const u16* __restrict__ Ahi, const u16* __restrict__ Alo,
    const u16* __restrict__ qkvT,
    const float* __restrict__ bq, const float* __restrict__ bk, const float* __restrict__ bv,
    float* __restrict__ Cbase) {
  constexpr int KD = 1024;
  __shared__ alignas(16) u16 As[2][2][128 * 32];  // [buf][hi/lo]
  __shared__ alignas(16) u16 Bs[2][2][128 * 32];
  const int tid = threadIdx.x;
  const int w = tid >> 6, lane = tid & 63;
  const int bm = blockIdx.x, bn = blockIdx.y, z = blockIdx.z;
  const u16* Bhi = qkvT + (size_t)z * (2u * KD * KD);
  const u16* Blo = Bhi + (size_t)KD * KD;
  const float* bias = (z == 0) ? bq : (z == 1) ? bk : bv;
  float* C = Cbase + (size_t)z * TOK * KD;

  int rowA[2], qA[2], rowB[2];
#pragma unroll
  for (int i = 0; i < 2; i++) {
    int c = (w * 2 + i) * 64 + lane;
    int r = c >> 2;
    qA[i] = c & 3;
    rowB[i] = bn * 128 + r;
    rowA[i] = bm * 128 + r;
  }

  auto stage = [&](int buf, int k0) {
#pragma unroll
    for (int i = 0; i < 2; i++) {
      size_t ga = (size_t)rowA[i] * KD + k0 + qA[i] * 8;
      size_t gb = (size_t)rowB[i] * KD + k0 + qA[i] * 8;
      int lo_off = (w * 2 + i) * 1024;
      gload16(Ahi + ga, (char*)&As[buf][0][0] + lo_off);
      gload16(Alo + ga, (char*)&As[buf][1][0] + lo_off);
      gload16(Bhi + gb, (char*)&Bs[buf][0][0] + lo_off);
      gload16(Blo + gb, (char*)&Bs[buf][1][0] + lo_off);
    }
  };

  f32x4 acc[4][4];
#pragma unroll
  for (int m = 0; m < 4; m++)
#pragma unroll
    for (int n = 0; n < 4; n++) acc[m][n] = (f32x4)0.f;

  const int wr = (w >> 1) * 64, wc = (w & 1) * 64;
  const int la = lane & 15, lk = (lane >> 4) * 8;

  stage(0, 0);
  __syncthreads();
  for (int kt = 0; kt < 32; kt++) {
    const int cur = kt & 1;
    if (kt + 1 < 32) stage(cur ^ 1, (kt + 1) * 32);
    short8 ah[4], al[4], bh[4], bl[4];
#pragma unroll
    for (int m = 0; m < 4; m++) {
      ah[m] = *(const short8*)&As[cur][0][(wr + m * 16 + la) * 32 + lk];
      al[m] = *(const short8*)&As[cur][1][(wr + m * 16 + la) * 32 + lk];
    }
#pragma unroll
    for (int n = 0; n < 4; n++) {
      bh[n] = *(const short8*)&Bs[cur][0][(wc + n * 16 + la) * 32 + lk];
      bl[n] = *(const short8*)&Bs[cur][1][(wc + n * 16 + la) * 32 + lk];
    }
#pragma unroll
    for (int m = 0; m < 4; m++)
#pragma unroll
      for (int n = 0; n < 4; n++) {
        acc[m][n] = __builtin_amdgcn_mfma_f32_16x16x32_bf16(ah[m], bh[n], acc[m][n], 0, 0, 0);
        acc[m][n] = __builtin_amdgcn_mfma_f32_16x16x32_bf16(ah[m], bl[n], acc[m][n], 0, 0, 0);
        acc[m][n] = __builtin_amdgcn_mfma_f32_16x16x32_bf16(al[m], bh[n], acc[m][n], 0, 0, 0);
      }
    __syncthreads();
  }

  const int rl4 = (lane >> 4) * 4;
#pragma unroll
  for (int m = 0; m < 4; m++) {
#pragma unroll
    for (int n = 0; n < 4; n++) {
      const int col = bn * 128 + wc + n * 16 + la;
      const float bvv = bias[col];
      f32x4 a4 = acc[m][n];
#pragma unroll
      for (int r = 0; r < 4; r++) {
        const int grow = bm * 128 + wr + m * 16 + rl4 + r;
        C[(size_t)grow * KD + col] = a4[r] + bvv;
      }
    }
  }
}

// ---------------- MoE GEMM, 128x128 tile, BK=32, z = expert
// MODE 1: gathered token rows, gelu(.+b1) -> h_buf rows segoff+pos
// MODE 2: A = h_buf rows, (.+b2)*gate -> atomicAdd scatter into out
template <int MODE>
__global__ __launch_bounds__(256) void k_gemm(
    const u16* __restrict__ A, const u16* __restrict__ BT, const float* __restrict__ bias,
    u16* __restrict__ Cb, float* __restrict__ Cf,
    const int* __restrict__ lists, const int* __restrict__ counts,
    const float* __restrict__ gatesp, const int* __restrict__ segoff) {
  constexpr int KD = 1024;
  __shared__ alignas(16) u16 As[2][128 * 32];
  __shared__ alignas(16) u16 Bs[2][128 * 32];

  int e = (int)blockIdx.z;
  int count = counts[e];
  if ((int)blockIdx.x * 128 >= count) return;
  const int* list = lists + (size_t)e * TOK;
  int so = segoff[e];
  const u16* Bp = BT + (size_t)e * (KD * KD);
  const float* bp = bias + (size_t)e * KD;

  const int tid = threadIdx.x;
  const int w = tid >> 6, lane = tid & 63;
  const int bm = blockIdx.x, bn = blockIdx.y;

  int rowA[2], qA[2], rowB[2];
#pragma unroll
  for (int i = 0; i < 2; i++) {
    int c = (w * 2 + i) * 64 + lane;
    int r = c >> 2;
    qA[i] = c & 3;
    rowB[i] = bn * 128 + r;
    int rr = bm * 128 + r;
    if constexpr (MODE == 1) rowA[i] = (rr < count) ? list[rr] : 0;
    else                     rowA[i] = so + ((rr < count) ? rr : 0);
  }

  auto stage = [&](int buf, int k0) {
#pragma unroll
    for (int i = 0; i < 2; i++) {
      gload16(A + (size_t)rowA[i] * KD + k0 + qA[i] * 8,
              (char*)&As[buf][0] + (w * 2 + i) * 1024);
      gload16(Bp + (size_t)rowB[i] * KD + k0 + qA[i] * 8,
              (char*)&Bs[buf][0] + (w * 2 + i) * 1024);
    }
  };

  f32x4 acc[4][4];
#pragma unroll
  for (int m = 0; m < 4; m++)
#pragma unroll
    for (int n = 0; n < 4; n++) acc[m][n] = (f32x4)0.f;

  const int wr = (w >> 1) * 64, wc = (w & 1) * 64;
  const int la = lane & 15, lk = (lane >> 4) * 8;

  stage(0, 0);
  __syncthreads();
#pragma unroll 2
  for (int kt = 0; kt < 32; kt++) {
    const int cur = kt & 1;
    if (kt + 1 < 32) stage(cur ^ 1, (kt + 1) * 32);
    short8 af[4], bf8[4];
#pragma unroll
    for (int m = 0; m < 4; m++)
      af[m] = *(const short8*)&As[cur][(wr + m * 16 + la) * 32 + lk];
#pragma unroll
    for (int n = 0; n < 4; n++)
      bf8[n] = *(const short8*)&Bs[cur][(wc + n * 16 + la) * 32 + lk];
#pragma unroll
    for (int m = 0; m < 4; m++)
#pragma unroll
      for (int n = 0; n < 4; n++)
        acc[m][n] = __builtin_amdgcn_mfma_f32_16x16x32_bf16(af[m], bf8[n], acc[m][n], 0, 0, 0);
    __syncthreads();
  }

  const int rl4 = (lane >> 4) * 4;
#pragma unroll
  for (int m = 0; m < 4; m++) {
#pragma unroll
    for (int n = 0; n < 4; n++) {
      const int col = bn * 128 + wc + n * 16 + la;
      const float bvv = bp[col];
      f32x4 a4 = acc[m][n];
#pragma unroll
      for (int r = 0; r < 4; r++) {
        const int grow = bm * 128 + wr + m * 16 + rl4 + r;
        float v = a4[r] + bvv;
        if constexpr (MODE == 1) {
          if (grow < count) {
            float gx = 0.5f * v * (1.0f + erff(v * 0.70710678f));
            Cb[(size_t)(so + grow) * KD + col] = f2bf(gx);
          }
        } else {
          if (grow < count) {
            const int tok = list[grow];
            const float gw = gatesp[(size_t)tok * 32 + e];
            atomicAdd(Cf + (size_t)tok * KD + col, v * gw);
          }
        }
      }
    }
  }
}

extern "C" void kernel_launch(void* const* d_in, const int* in_sizes, int n_in,
                              void* d_out, int out_size, void* d_ws, size_t ws_size,
                              hipStream_t stream) {
  (void)in_sizes; (void)n_in; (void)out_size; (void)ws_size;
  const float* hidden = (const float*)d_in[0];
  const float* ln1s = (const float*)d_in[1];
  const float* ln1b = (const float*)d_in[2];
  const float* wq = (const float*)d_in[3];
  const float* bq = (const float*)d_in[4];
  const float* wk = (const float*)d_in[5];
  const float* bk = (const float*)d_in[6];
  const float* wv = (const float*)d_in[7];
  const float* bv = (const float*)d_in[8];
  const float* ln2s = (const float*)d_in[9];
  const float* ln2b = (const float*)d_in[10];
  const float* rw = (const float*)d_in[11];
  const float* rb = (const float*)d_in[12];
  const float* w1 = (const float*)d_in[13];
  const float* b1 = (const float*)d_in[14];
  const float* w2 = (const float*)d_in[15];
  const float* b2 = (const float*)d_in[16];
  float* out = (float*)d_out;

  char* wsp = (char*)d_ws;
  size_t off = 0;
  auto alloc = [&](size_t b) -> void* {
    void* p = wsp + off;
    off += (b + 255) & ~(size_t)255;
    return p;
  };
  // persistent region (~100.3 MB)
  u16* wT = (u16*)alloc((size_t)NE * DD * DD * 2);        // 64 MB: w1T, later w2T
  u16* x_hi = (u16*)alloc((size_t)TOK * DD * 2);          // 32 MB: ln1-hi, later x2
  float* gates = (float*)alloc((size_t)TOK * NE * 4);     // 2 MB
  int* counts = (int*)alloc(NE * 4);
  int* segoff = (int*)alloc((NE + 1) * 4);
  int* lists = (int*)alloc((size_t)NE * TOK * 4);         // 2 MB
  // pool region (256 MB): phase A = {qkvT split 12MB | x_lo 32MB | q/k/v fp32 192MB},
  //                       phase B = h_buf (131072 rows x 1024 bf16, exactly 256MB)
  char* pool = (char*)alloc((size_t)TOK * 8 * DD * 2);
  u16* qkvT = (u16*)pool;                                   // 3 * 2 * 2MB
  u16* x_lo = (u16*)(pool + 12u * 1024 * 1024);             // 32 MB
  float* qkv = (float*)(pool + 44u * 1024 * 1024);          // 3 * 64 MB fp32
  float* qbuf = qkv;
  float* kbuf = qkv + (size_t)TOK * DD;
  float* vbuf = qkv + 2 * (size_t)TOK * DD;
  u16* h_buf = (u16*)pool;

  dim3 tb32(32, 8, 1);
  k_zero32<<<1, 64, 0, stream>>>(counts);
  k_transpose_split<<<dim3(32, 32, 1), tb32, 0, stream>>>(wq, qkvT, qkvT + (size_t)DD * DD, DD, DD);
  k_transpose_split<<<dim3(32, 32, 1), tb32, 0, stream>>>(wk, qkvT + 2 * (size_t)DD * DD, qkvT + 3 * (size_t)DD * DD, DD, DD);
  k_transpose_split<<<dim3(32, 32, 1), tb32, 0, stream>>>(wv, qkvT + 4 * (size_t)DD * DD, qkvT + 5 * (size_t)DD * DD, DD, DD);
  k_transpose<<<dim3(32, 32, NE), tb32, 0, stream>>>(w1, wT, DD, DD);
  k_ln1<<<TOK, 256, 0, stream>>>(hidden, ln1s, ln1b, x_hi, x_lo);
  k_gemm_p<<<dim3(128, 8, 3), 256, 0, stream>>>(x_hi, x_lo, qkvT, bq, bk, bv, qkv);
  k_attn<<<TOK, 256, 0, stream>>>(hidden, qbuf, kbuf, vbuf, ln2s, ln2b, rw, rb, out, x_hi, gates);
  k_listbuild<<<TOK / 256, 256, 0, stream>>>(gates, counts, lists);
  k_scan<<<1, 32, 0, stream>>>(counts, segoff);
  k_gemm<1><<<dim3(128, 8, NE), 256, 0, stream>>>(x_hi, wT, b1, h_buf, nullptr, lists, counts, nullptr, segoff);
  k_transpose<<<dim3(32, 32, NE), tb32, 0, stream>>>(w2, wT, DD, DD);
  k_gemm<2><<<dim3(128, 8, NE), 256, 0, stream>>>(h_buf, wT, b2, nullptr, out, lists, counts, gates, segoff);
}

// Round 4
// 2037.420 us; speedup vs baseline: 2.4663x; 1.2425x over previous
//
#include <hip/hip_runtime.h>
#include <hip/hip_bf16.h>
#include <stdint.h>

#define TOK 16384   // B*S
#define DD  1024    // D = F = 1024
#define NE  32      // experts

typedef unsigned short u16;
typedef __attribute__((ext_vector_type(8))) short short8;
typedef __attribute__((ext_vector_type(4))) float f32x4;

__device__ __forceinline__ u16 f2bf(float f) {
  unsigned int u = __float_as_uint(f);
  u += 0x7fffu + ((u >> 16) & 1u);
  return (u16)(u >> 16);
}
__device__ __forceinline__ float bf2f(u16 h) {
  return __uint_as_float(((unsigned int)h) << 16);
}
__device__ __forceinline__ void gload16(const void* g, void* l) {
  __builtin_amdgcn_global_load_lds((const __attribute__((address_space(1))) void*)g,
                                   (__attribute__((address_space(3))) void*)l, 16, 0, 0);
}

// ---------------- transpose + convert: src[z][R][C] f32 -> dst[z][C][R] bf16
__global__ __launch_bounds__(256) void k_transpose(const float* __restrict__ src,
                                                   u16* __restrict__ dst, int R, int C) {
  __shared__ float tile[32][33];
  size_t mb = (size_t)blockIdx.z * R * C;
  int c0 = blockIdx.x * 32, r0 = blockIdx.y * 32;
  int tx = threadIdx.x, ty = threadIdx.y;
#pragma unroll
  for (int i = 0; i < 4; i++)
    tile[ty + i * 8][tx] = src[mb + (size_t)(r0 + ty + i * 8) * C + c0 + tx];
  __syncthreads();
#pragma unroll
  for (int i = 0; i < 4; i++) {
    float v = tile[tx][ty + i * 8];
    dst[mb + (size_t)(c0 + ty + i * 8) * R + r0 + tx] = f2bf(v);
  }
}

// ---------------- transpose + split into bf16 hi/lo pair: dst[C][R]
__global__ __launch_bounds__(256) void k_transpose_split(const float* __restrict__ src,
                                                         u16* __restrict__ hi,
                                                         u16* __restrict__ lo, int R, int C) {
  __shared__ float tile[32][33];
  int c0 = blockIdx.x * 32, r0 = blockIdx.y * 32;
  int tx = threadIdx.x, ty = threadIdx.y;
#pragma unroll
  for (int i = 0; i < 4; i++)
    tile[ty + i * 8][tx] = src[(size_t)(r0 + ty + i * 8) * C + c0 + tx];
  __syncthreads();
#pragma unroll
  for (int i = 0; i < 4; i++) {
    float v = tile[tx][ty + i * 8];
    u16 h = f2bf(v);
    u16 l = f2bf(v - bf2f(h));
    size_t idx = (size_t)(c0 + ty + i * 8) * R + r0 + tx;
    hi[idx] = h;
    lo[idx] = l;
  }
}

// ---------------- LN1: x = LN(hidden) -> bf16 hi/lo pair
__global__ __launch_bounds__(256) void k_ln1(const float* __restrict__ x,
                                             const float* __restrict__ sc,
                                             const float* __restrict__ bi,
                                             u16* __restrict__ ohi, u16* __restrict__ olo) {
  __shared__ float red[10];
  int t = blockIdx.x, tid = threadIdx.x;
  size_t base = (size_t)t * DD + tid * 4;
  float4 v = *(const float4*)(x + base);
  float s1 = v.x + v.y + v.z + v.w;
  float s2 = v.x * v.x + v.y * v.y + v.z * v.z + v.w * v.w;
  for (int o = 1; o < 64; o <<= 1) { s1 += __shfl_xor(s1, o, 64); s2 += __shfl_xor(s2, o, 64); }
  int wid = tid >> 6;
  if ((tid & 63) == 0) { red[wid * 2] = s1; red[wid * 2 + 1] = s2; }
  __syncthreads();
  if (tid == 0) {
    float a = 0, b = 0;
    for (int i = 0; i < 4; i++) { a += red[i * 2]; b += red[i * 2 + 1]; }
    float mean = a * (1.f / DD);
    float var = b * (1.f / DD) - mean * mean;
    red[8] = mean; red[9] = rsqrtf(var + 1e-5f);
  }
  __syncthreads();
  float mean = red[8], rs = red[9];
  int e0 = tid * 4;
  float xv[4] = {v.x, v.y, v.z, v.w};
  ushort4 oh, ol;
  u16* ph = (u16*)&oh; u16* pl = (u16*)&ol;
#pragma unroll
  for (int i = 0; i < 4; i++) {
    float f = (xv[i] - mean) * rs * sc[e0 + i] + bi[e0 + i];
    u16 h = f2bf(f);
    ph[i] = h;
    pl[i] = f2bf(f - bf2f(h));
  }
  *(ushort4*)(ohi + base) = oh;
  *(ushort4*)(olo + base) = ol;
}

// ---------------- fused: per-token head attention + residual + LN2 + router + top-8 gates
__global__ __launch_bounds__(256) void k_attn(
    const float* __restrict__ hidden, const float* __restrict__ qb,
    const float* __restrict__ kb, const float* __restrict__ vb,
    const float* __restrict__ ln2s, const float* __restrict__ ln2b,
    const float* __restrict__ rw, const float* __restrict__ rb,
    float* __restrict__ out, u16* __restrict__ x2b, float* __restrict__ gates) {
  __shared__ float qs[16][68], ks[16][68], vs[16][68];
  __shared__ float probs[16][17];
  __shared__ float x2s[1024];
  __shared__ float red[12];
  __shared__ float part[8][32];
  int t = blockIdx.x, tid = threadIdx.x;
  size_t base = (size_t)t * DD + tid * 4;
  int hh = tid >> 4, dd = (tid & 15) * 4;
  {
    float4 q4 = *(const float4*)(qb + base);
    float4 k4 = *(const float4*)(kb + base);
    float4 v4 = *(const float4*)(vb + base);
    qs[hh][dd + 0] = q4.x; qs[hh][dd + 1] = q4.y; qs[hh][dd + 2] = q4.z; qs[hh][dd + 3] = q4.w;
    ks[hh][dd + 0] = k4.x; ks[hh][dd + 1] = k4.y; ks[hh][dd + 2] = k4.z; ks[hh][dd + 3] = k4.w;
    vs[hh][dd + 0] = v4.x; vs[hh][dd + 1] = v4.y; vs[hh][dd + 2] = v4.z; vs[hh][dd + 3] = v4.w;
  }
  __syncthreads();
  {
    int g = tid & 15;
    float s = 0.f;
#pragma unroll
    for (int d = 0; d < 64; d++) s += qs[hh][d] * ks[g][d];
    s *= 0.125f;
    float mx = s;
    for (int o = 1; o < 16; o <<= 1) mx = fmaxf(mx, __shfl_xor(mx, o, 16));
    float p = __expf(s - mx);
    float sm = p;
    for (int o = 1; o < 16; o <<= 1) sm += __shfl_xor(sm, o, 16);
    probs[hh][g] = p / sm;
  }
  __syncthreads();
  float c0 = 0, c1 = 0, c2 = 0, c3 = 0;
#pragma unroll
  for (int g = 0; g < 16; g++) {
    float pw = probs[hh][g];
    c0 += pw * vs[g][dd + 0]; c1 += pw * vs[g][dd + 1];
    c2 += pw * vs[g][dd + 2]; c3 += pw * vs[g][dd + 3];
  }
  float4 hv = *(const float4*)(hidden + base);
  float h0 = hv.x + c0, h1 = hv.y + c1, h2 = hv.z + c2, h3 = hv.w + c3;
  { float4 o4; o4.x = h0; o4.y = h1; o4.z = h2; o4.w = h3; *(float4*)(out + base) = o4; }
  float s1 = h0 + h1 + h2 + h3;
  float s2 = h0 * h0 + h1 * h1 + h2 * h2 + h3 * h3;
  for (int o = 1; o < 64; o <<= 1) { s1 += __shfl_xor(s1, o, 64); s2 += __shfl_xor(s2, o, 64); }
  int wid = tid >> 6;
  if ((tid & 63) == 0) { red[wid * 2] = s1; red[wid * 2 + 1] = s2; }
  __syncthreads();
  if (tid == 0) {
    float a = 0, b = 0;
    for (int i = 0; i < 4; i++) { a += red[i * 2]; b += red[i * 2 + 1]; }
    float mean = a * (1.f / DD);
    float var = b * (1.f / DD) - mean * mean;
    red[8] = mean; red[9] = rsqrtf(var + 1e-5f);
  }
  __syncthreads();
  float mean = red[8], rs = red[9];
  int e0 = tid * 4;
  float x0 = (h0 - mean) * rs * ln2s[e0 + 0] + ln2b[e0 + 0];
  float x1 = (h1 - mean) * rs * ln2s[e0 + 1] + ln2b[e0 + 1];
  float x2 = (h2 - mean) * rs * ln2s[e0 + 2] + ln2b[e0 + 2];
  float x3 = (h3 - mean) * rs * ln2s[e0 + 3] + ln2b[e0 + 3];
  ushort4 xo; xo.x = f2bf(x0); xo.y = f2bf(x1); xo.z = f2bf(x2); xo.w = f2bf(x3);
  *(ushort4*)(x2b + base) = xo;
  x2s[e0 + 0] = x0; x2s[e0 + 1] = x1; x2s[e0 + 2] = x2; x2s[e0 + 3] = x3;
  __syncthreads();
  {
    // router GEMV: e = tid&31 (coalesced rw), seg = tid>>5 (x2s broadcast)
    int e = tid & 31, seg = tid >> 5;
    const float* rwp = rw + (size_t)(seg * 128) * NE + e;
    float acc = 0.f;
#pragma unroll 8
    for (int i = 0; i < 128; i++) acc += x2s[seg * 128 + i] * rwp[(size_t)i * NE];
    part[seg][e] = acc;
  }
  __syncthreads();
  if (tid < 32) {
    float l = rb[tid];
#pragma unroll
    for (int s = 0; s < 8; s++) l += part[s][tid];
    float mx = l;
    for (int o = 1; o < 32; o <<= 1) mx = fmaxf(mx, __shfl_xor(mx, o, 32));
    float p = __expf(l - mx);
    float sm = p;
    for (int o = 1; o < 32; o <<= 1) sm += __shfl_xor(sm, o, 32);
    p /= sm;
    bool sel = false;
#pragma unroll
    for (int rsel = 0; rsel < 8; rsel++) {
      float bv = sel ? -1.f : p;
      int bi_ = tid;
      for (int o = 1; o < 32; o <<= 1) {
        float ov = __shfl_xor(bv, o, 32);
        int oi = __shfl_xor(bi_, o, 32);
        if (ov > bv || (ov == bv && oi < bi_)) { bv = ov; bi_ = oi; }
      }
      if (tid == bi_) sel = true;
    }
    float wsel = sel ? p : 0.f;
    float ts = wsel;
    for (int o = 1; o < 32; o <<= 1) ts += __shfl_xor(ts, o, 32);
    gates[(size_t)t * 32 + tid] = sel ? (p / ts) : 0.f;
  }
}

__global__ void k_zero32(int* p) { int i = threadIdx.x; if (i < 32) p[i] = 0; }

// build per-expert token lists + per-token (expert,pos) slots + gate values
__global__ void k_listbuild(const float* __restrict__ gates, int* __restrict__ counts,
                            int* __restrict__ lists, int* __restrict__ slots,
                            float* __restrict__ gsel) {
  int t = blockIdx.x * 256 + threadIdx.x;
  int j = 0;
  for (int e = 0; e < NE; e++) {
    float g = gates[(size_t)t * 32 + e];
    if (g > 0.f && j < 8) {
      int pos = atomicAdd(&counts[e], 1);
      lists[(size_t)e * TOK + pos] = t;
      slots[t * 8 + j] = (e << 14) | pos;
      gsel[t * 8 + j] = g;
      j++;
    }
  }
}

__global__ void k_scan(const int* __restrict__ counts, int* __restrict__ segoff) {
  if (threadIdx.x == 0) { int s = 0; for (int e = 0; e < NE; e++) { segoff[e] = s; s += counts[e]; } }
}

// ---------------- precise GEMM (split bf16), z = matrix select (Q/K/V)
__global__ __launch_bounds__(256) void k_gemm_p(
    const u16* __restrict__ Ahi, const u16* __restrict__ Alo,
    const u16* __restrict__ qkvT,
    const float* __restrict__ bq, const float* __restrict__ bk, const float* __restrict__ bv,
    float* __restrict__ Cbase) {
  constexpr int KD = 1024;
  __shared__ alignas(16) u16 As[2][2][128 * 32];  // [buf][hi/lo]
  __shared__ alignas(16) u16 Bs[2][2][128 * 32];
  const int tid = threadIdx.x;
  const int w = tid >> 6, lane = tid & 63;
  const int bm = blockIdx.x, bn = blockIdx.y, z = blockIdx.z;
  const u16* Bhi = qkvT + (size_t)z * (2u * KD * KD);
  const u16* Blo = Bhi + (size_t)KD * KD;
  const float* bias = (z == 0) ? bq : (z == 1) ? bk : bv;
  float* C = Cbase + (size_t)z * TOK * KD;

  int rowA[2], qA[2], rowB[2];
#pragma unroll
  for (int i = 0; i < 2; i++) {
    int c = (w * 2 + i) * 64 + lane;
    int r = c >> 2;
    qA[i] = c & 3;
    rowB[i] = bn * 128 + r;
    rowA[i] = bm * 128 + r;
  }

  auto stage = [&](int buf, int k0) {
#pragma unroll
    for (int i = 0; i < 2; i++) {
      size_t ga = (size_t)rowA[i] * KD + k0 + qA[i] * 8;
      size_t gb = (size_t)rowB[i] * KD + k0 + qA[i] * 8;
      int lo_off = (w * 2 + i) * 1024;
      gload16(Ahi + ga, (char*)&As[buf][0][0] + lo_off);
      gload16(Alo + ga, (char*)&As[buf][1][0] + lo_off);
      gload16(Bhi + gb, (char*)&Bs[buf][0][0] + lo_off);
      gload16(Blo + gb, (char*)&Bs[buf][1][0] + lo_off);
    }
  };

  f32x4 acc[4][4];
#pragma unroll
  for (int m = 0; m < 4; m++)
#pragma unroll
    for (int n = 0; n < 4; n++) acc[m][n] = (f32x4)0.f;

  const int wr = (w >> 1) * 64, wc = (w & 1) * 64;
  const int la = lane & 15, lk = (lane >> 4) * 8;

  stage(0, 0);
  __syncthreads();
  for (int kt = 0; kt < 32; kt++) {
    const int cur = kt & 1;
    if (kt + 1 < 32) stage(cur ^ 1, (kt + 1) * 32);
    short8 ah[4], al[4], bh[4], bl[4];
#pragma unroll
    for (int m = 0; m < 4; m++) {
      ah[m] = *(const short8*)&As[cur][0][(wr + m * 16 + la) * 32 + lk];
      al[m] = *(const short8*)&As[cur][1][(wr + m * 16 + la) * 32 + lk];
    }
#pragma unroll
    for (int n = 0; n < 4; n++) {
      bh[n] = *(const short8*)&Bs[cur][0][(wc + n * 16 + la) * 32 + lk];
      bl[n] = *(const short8*)&Bs[cur][1][(wc + n * 16 + la) * 32 + lk];
    }
#pragma unroll
    for (int m = 0; m < 4; m++)
#pragma unroll
      for (int n = 0; n < 4; n++) {
        acc[m][n] = __builtin_amdgcn_mfma_f32_16x16x32_bf16(ah[m], bh[n], acc[m][n], 0, 0, 0);
        acc[m][n] = __builtin_amdgcn_mfma_f32_16x16x32_bf16(ah[m], bl[n], acc[m][n], 0, 0, 0);
        acc[m][n] = __builtin_amdgcn_mfma_f32_16x16x32_bf16(al[m], bh[n], acc[m][n], 0, 0, 0);
      }
    __syncthreads();
  }

  const int rl4 = (lane >> 4) * 4;
#pragma unroll
  for (int m = 0; m < 4; m++) {
#pragma unroll
    for (int n = 0; n < 4; n++) {
      const int col = bn * 128 + wc + n * 16 + la;
      const float bvv = bias[col];
      f32x4 a4 = acc[m][n];
#pragma unroll
      for (int r = 0; r < 4; r++) {
        const int grow = bm * 128 + wr + m * 16 + rl4 + r;
        C[(size_t)grow * KD + col] = a4[r] + bvv;
      }
    }
  }
}

// ---------------- MoE GEMM1: gathered token rows, gelu(.+b1) -> h_buf segment rows
__global__ __launch_bounds__(256) void k_gemm1(
    const u16* __restrict__ A, const u16* __restrict__ BT, const float* __restrict__ bias,
    u16* __restrict__ Cb, const int* __restrict__ lists, const int* __restrict__ counts,
    const int* __restrict__ segoff) {
  constexpr int KD = 1024;
  __shared__ alignas(16) u16 As[2][128 * 32];
  __shared__ alignas(16) u16 Bs[2][128 * 32];

  int e = (int)blockIdx.z;
  int count = counts[e];
  if ((int)blockIdx.x * 128 >= count) return;
  const int* list = lists + (size_t)e * TOK;
  int so = segoff[e];
  const u16* Bp = BT + (size_t)e * (KD * KD);
  const float* bp = bias + (size_t)e * KD;

  const int tid = threadIdx.x;
  const int w = tid >> 6, lane = tid & 63;
  const int bm = blockIdx.x, bn = blockIdx.y;

  int rowA[2], qA[2], rowB[2];
#pragma unroll
  for (int i = 0; i < 2; i++) {
    int c = (w * 2 + i) * 64 + lane;
    int r = c >> 2;
    qA[i] = c & 3;
    rowB[i] = bn * 128 + r;
    int rr = bm * 128 + r;
    rowA[i] = (rr < count) ? list[rr] : 0;
  }

  auto stage = [&](int buf, int k0) {
#pragma unroll
    for (int i = 0; i < 2; i++) {
      gload16(A + (size_t)rowA[i] * KD + k0 + qA[i] * 8,
              (char*)&As[buf][0] + (w * 2 + i) * 1024);
      gload16(Bp + (size_t)rowB[i] * KD + k0 + qA[i] * 8,
              (char*)&Bs[buf][0] + (w * 2 + i) * 1024);
    }
  };

  f32x4 acc[4][4];
#pragma unroll
  for (int m = 0; m < 4; m++)
#pragma unroll
    for (int n = 0; n < 4; n++) acc[m][n] = (f32x4)0.f;

  const int wr = (w >> 1) * 64, wc = (w & 1) * 64;
  const int la = lane & 15, lk = (lane >> 4) * 8;

  stage(0, 0);
  __syncthreads();
#pragma unroll 2
  for (int kt = 0; kt < 32; kt++) {
    const int cur = kt & 1;
    if (kt + 1 < 32) stage(cur ^ 1, (kt + 1) * 32);
    short8 af[4], bf8[4];
#pragma unroll
    for (int m = 0; m < 4; m++)
      af[m] = *(const short8*)&As[cur][(wr + m * 16 + la) * 32 + lk];
#pragma unroll
    for (int n = 0; n < 4; n++)
      bf8[n] = *(const short8*)&Bs[cur][(wc + n * 16 + la) * 32 + lk];
#pragma unroll
    for (int m = 0; m < 4; m++)
#pragma unroll
      for (int n = 0; n < 4; n++)
        acc[m][n] = __builtin_amdgcn_mfma_f32_16x16x32_bf16(af[m], bf8[n], acc[m][n], 0, 0, 0);
    __syncthreads();
  }

  const int rl4 = (lane >> 4) * 4;
#pragma unroll
  for (int m = 0; m < 4; m++) {
#pragma unroll
    for (int n = 0; n < 4; n++) {
      const int col = bn * 128 + wc + n * 16 + la;
      const float bvv = bp[col];
      f32x4 a4 = acc[m][n];
#pragma unroll
      for (int r = 0; r < 4; r++) {
        const int grow = bm * 128 + wr + m * 16 + rl4 + r;
        if (grow < count) {
          float v = a4[r] + bvv;
          float gx = 0.5f * v * (1.0f + erff(v * 0.70710678f));
          Cb[(size_t)(so + grow) * KD + col] = f2bf(gx);
        }
      }
    }
  }
}

// ---------------- MoE GEMM2: segment rows in, (.+b2) -> bf16 out2 (col chunk [col0,col0+C))
__global__ __launch_bounds__(256) void k_gemm2(
    const u16* __restrict__ A, const u16* __restrict__ BT, const float* __restrict__ bias,
    u16* __restrict__ out2, const int* __restrict__ counts, const int* __restrict__ segoff,
    int col0, int C) {
  constexpr int KD = 1024;
  __shared__ alignas(16) u16 As[2][128 * 32];
  __shared__ alignas(16) u16 Bs[2][128 * 32];

  int e = (int)blockIdx.z;
  int count = counts[e];
  if ((int)blockIdx.x * 128 >= count) return;
  int so = segoff[e];
  const u16* Bp = BT + (size_t)e * (KD * KD);
  const float* bp = bias + (size_t)e * KD;

  const int tid = threadIdx.x;
  const int w = tid >> 6, lane = tid & 63;
  const int bm = blockIdx.x, bn = blockIdx.y;

  int rowA[2], qA[2], rowB[2];
#pragma unroll
  for (int i = 0; i < 2; i++) {
    int c = (w * 2 + i) * 64 + lane;
    int r = c >> 2;
    qA[i] = c & 3;
    rowB[i] = col0 + bn * 128 + r;   // B row = global output col
    int rr = bm * 128 + r;
    rowA[i] = so + ((rr < count) ? rr : 0);
  }

  auto stage = [&](int buf, int k0) {
#pragma unroll
    for (int i = 0; i < 2; i++) {
      gload16(A + (size_t)rowA[i] * KD + k0 + qA[i] * 8,
              (char*)&As[buf][0] + (w * 2 + i) * 1024);
      gload16(Bp + (size_t)rowB[i] * KD + k0 + qA[i] * 8,
              (char*)&Bs[buf][0] + (w * 2 + i) * 1024);
    }
  };

  f32x4 acc[4][4];
#pragma unroll
  for (int m = 0; m < 4; m++)
#pragma unroll
    for (int n = 0; n < 4; n++) acc[m][n] = (f32x4)0.f;

  const int wr = (w >> 1) * 64, wc = (w & 1) * 64;
  const int la = lane & 15, lk = (lane >> 4) * 8;

  stage(0, 0);
  __syncthreads();
#pragma unroll 2
  for (int kt = 0; kt < 32; kt++) {
    const int cur = kt & 1;
    if (kt + 1 < 32) stage(cur ^ 1, (kt + 1) * 32);
    short8 af[4], bf8[4];
#pragma unroll
    for (int m = 0; m < 4; m++)
      af[m] = *(const short8*)&As[cur][(wr + m * 16 + la) * 32 + lk];
#pragma unroll
    for (int n = 0; n < 4; n++)
      bf8[n] = *(const short8*)&Bs[cur][(wc + n * 16 + la) * 32 + lk];
#pragma unroll
    for (int m = 0; m < 4; m++)
#pragma unroll
      for (int n = 0; n < 4; n++)
        acc[m][n] = __builtin_amdgcn_mfma_f32_16x16x32_bf16(af[m], bf8[n], acc[m][n], 0, 0, 0);
    __syncthreads();
  }

  const int rl4 = (lane >> 4) * 4;
#pragma unroll
  for (int m = 0; m < 4; m++) {
#pragma unroll
    for (int n = 0; n < 4; n++) {
      const int lcol = bn * 128 + wc + n * 16 + la;
      const float bvv = bp[col0 + lcol];
      f32x4 a4 = acc[m][n];
#pragma unroll
      for (int r = 0; r < 4; r++) {
        const int grow = bm * 128 + wr + m * 16 + rl4 + r;
        if (grow < count)
          out2[(size_t)(so + grow) * C + lcol] = f2bf(a4[r] + bvv);
      }
    }
  }
}

// ---------------- gather-reduce: out[t][col0+c] += sum_j gsel[t,j] * out2[seg_j][c]
__global__ __launch_bounds__(256) void k_gather(
    const float* __restrict__ gsel, const int* __restrict__ slots,
    const int* __restrict__ segoff, const u16* __restrict__ out2,
    float* __restrict__ out, int col0, int C, int cshift) {
  int tid4 = threadIdx.x * 4;
  int tpb = 1024 >> cshift;  // tokens per block
  int t = blockIdx.x * tpb + (tid4 >> cshift);
  int c4 = tid4 & (C - 1);
  float a0 = 0, a1 = 0, a2 = 0, a3 = 0;
#pragma unroll
  for (int j = 0; j < 8; j++) {
    int s = slots[t * 8 + j];
    float g = gsel[t * 8 + j];
    int seg = segoff[s >> 14] + (s & 16383);
    ushort4 v4 = *(const ushort4*)(out2 + (size_t)seg * C + c4);
    a0 += g * bf2f(v4.x); a1 += g * bf2f(v4.y);
    a2 += g * bf2f(v4.z); a3 += g * bf2f(v4.w);
  }
  size_t ob = (size_t)t * DD + col0 + c4;
  float4 o = *(const float4*)(out + ob);
  o.x += a0; o.y += a1; o.z += a2; o.w += a3;
  *(float4*)(out + ob) = o;
}

extern "C" void kernel_launch(void* const* d_in, const int* in_sizes, int n_in,
                              void* d_out, int out_size, void* d_ws, size_t ws_size,
                              hipStream_t stream) {
  (void)in_sizes; (void)n_in; (void)out_size;
  const float* hidden = (const float*)d_in[0];
  const float* ln1s = (const float*)d_in[1];
  const float* ln1b = (const float*)d_in[2];
  const float* wq = (const float*)d_in[3];
  const float* bq = (const float*)d_in[4];
  const float* wk = (const float*)d_in[5];
  const float* bk = (const float*)d_in[6];
  const float* wv = (const float*)d_in[7];
  const float* bv = (const float*)d_in[8];
  const float* ln2s = (const float*)d_in[9];
  const float* ln2b = (const float*)d_in[10];
  const float* rw = (const float*)d_in[11];
  const float* rb = (const float*)d_in[12];
  const float* w1 = (const float*)d_in[13];
  const float* b1 = (const float*)d_in[14];
  const float* w2 = (const float*)d_in[15];
  const float* b2 = (const float*)d_in[16];
  float* out = (float*)d_out;

  char* wsp = (char*)d_ws;
  size_t off = 0;
  auto alloc = [&](size_t b) -> void* {
    void* p = wsp + off;
    off += (b + 255) & ~(size_t)255;
    return p;
  };
  // persistent (survive into MoE tail)
  u16* wT = (u16*)alloc((size_t)NE * DD * DD * 2);        // 64 MB: w1T, later w2T
  int* slots = (int*)alloc((size_t)TOK * 8 * 4);          // 512 KB
  float* gsel = (float*)alloc((size_t)TOK * 8 * 4);       // 512 KB
  int* counts = (int*)alloc(NE * 4);
  int* segoff = (int*)alloc((NE + 1) * 4);
  // reclaimable region R (dead by GEMM2 time): 36 MB
  u16* x_hi = (u16*)alloc((size_t)TOK * DD * 2);          // 32 MB: ln1-hi, later x2
  float* gates = (float*)alloc((size_t)TOK * NE * 4);     // 2 MB
  int* lists = (int*)alloc((size_t)NE * TOK * 4);         // 2 MB
  // pool (256 MB): phase A = {qkvT split 12MB | x_lo 32MB | q/k/v fp32 192MB},
  //                phase B = h_buf (131072 x 1024 bf16)
  char* pool = (char*)alloc((size_t)TOK * 8 * DD * 2);
  u16* qkvT = (u16*)pool;
  u16* x_lo = (u16*)(pool + 12u * 1024 * 1024);
  float* qkv = (float*)(pool + 44u * 1024 * 1024);
  float* qbuf = qkv;
  float* kbuf = qkv + (size_t)TOK * DD;
  float* vbuf = qkv + 2 * (size_t)TOK * DD;
  u16* h_buf = (u16*)pool;

  // out2 sizing from actual ws_size: C cols per chunk, rows always 131072
  const size_t ROWS = (size_t)TOK * 8;
  size_t extra = (ws_size > off) ? ws_size - off : 0;
  int C;
  u16* out2;
  if (extra >= ROWS * 1024 * 2 + 1024) { C = 1024; out2 = (u16*)alloc(ROWS * 1024 * 2); }
  else if (extra >= ROWS * 512 * 2 + 1024) { C = 512; out2 = (u16*)alloc(ROWS * 512 * 2); }
  else if (extra >= ROWS * 256 * 2 + 1024) { C = 256; out2 = (u16*)alloc(ROWS * 256 * 2); }
  else { C = 128; out2 = (u16*)x_hi; }  // R region (36 MB) >= 32 MB needed
  int cshift = 31 - __builtin_clz((unsigned)C);

  dim3 tb32(32, 8, 1);
  k_zero32<<<1, 64, 0, stream>>>(counts);
  k_transpose_split<<<dim3(32, 32, 1), tb32, 0, stream>>>(wq, qkvT, qkvT + (size_t)DD * DD, DD, DD);
  k_transpose_split<<<dim3(32, 32, 1), tb32, 0, stream>>>(wk, qkvT + 2 * (size_t)DD * DD, qkvT + 3 * (size_t)DD * DD, DD, DD);
  k_transpose_split<<<dim3(32, 32, 1), tb32, 0, stream>>>(wv, qkvT + 4 * (size_t)DD * DD, qkvT + 5 * (size_t)DD * DD, DD, DD);
  k_transpose<<<dim3(32, 32, NE), tb32, 0, stream>>>(w1, wT, DD, DD);
  k_ln1<<<TOK, 256, 0, stream>>>(hidden, ln1s, ln1b, x_hi, x_lo);
  k_gemm_p<<<dim3(128, 8, 3), 256, 0, stream>>>(x_hi, x_lo, qkvT, bq, bk, bv, qkv);
  k_attn<<<TOK, 256, 0, stream>>>(hidden, qbuf, kbuf, vbuf, ln2s, ln2b, rw, rb, out, x_hi, gates);
  k_listbuild<<<TOK / 256, 256, 0, stream>>>(gates, counts, lists, slots, gsel);
  k_scan<<<1, 32, 0, stream>>>(counts, segoff);
  k_gemm1<<<dim3(128, 8, NE), 256, 0, stream>>>(x_hi, wT, b1, h_buf, lists, counts, segoff);
  k_transpose<<<dim3(32, 32, NE), tb32, 0, stream>>>(w2, wT, DD, DD);
  for (int c0 = 0; c0 < DD; c0 += C) {
    k_gemm2<<<dim3(128, C / 128, NE), 256, 0, stream>>>(h_buf, wT, b2, out2, counts, segoff, c0, C);
    k_gather<<<TOK >> (10 - cshift), 256, 0, stream>>>(gsel, slots, segoff, out2, out, c0, C, cshift);
  }
}